// Round 10
// baseline (411.025 us; speedup 1.0000x reference)
//
#include <hip/hip_runtime.h>
#include <hip/hip_fp16.h>

// DSS bundle propagation: 3 graphs x (2-layer SpMM + L2norm + average).
// R15: SpMM MLP fix. R9 counters: spmm_l2 at 99us with VGPR_Count=32 --
// the unroll-4 loop needs ~50 regs to keep 4 gathers in flight, so the
// compiler SERIALIZED the load-use chains (MLP ~1-2); HBM 49%, VALU 38%,
// occ 73% = latency-bound, nothing saturated. Fix: __launch_bounds__(256,4)
// (VGPR cap 128) + 8-edge unroll structured {8 ev loads -> 8 offs ->
// 8 b128 gathers -> 64 FMIX} -> ~8 outstanding gathers/wave, 16 waves/CU.
// Partition (1024-row buckets, NPB=170) + reg-staged finalize from R14.
//
// Output rows: [UI_u(U) | UB_u(U) | BI_b(NB) | UB_b(NB) | UI_i(NI) | BI_i(NI)]

#define D 64
#define SB_SHIFT 10
#define SB_ROWS 1024
#define PACK_SHIFT 20      // rec.x = (row_local << 20) | col; col < 2^20
#define MAX_NSB 160        // >= ceil(150000/1024) = 147 (max per-graph)
#define NPB 170            // partition blocks per graph (510 total, 2/CU)
#define PART_T 1024        // threads per partition block
#define CAPB 16384         // arena slots per bucket (max mean ~14.6K, +15 sigma)
#define FIN_T 1024
#define F1_SCALE 4096.0f

// f32 acc += f32 v * f16 half of dword h (lo / hi). VOP3P v_fma_mix_f32.
#define FMIX_LO(acc, vf, hw) \
    asm("v_fma_mix_f32 %0, %1, %2, %0 op_sel:[0,0,0] op_sel_hi:[0,1,0]" \
        : "+v"(acc) : "v"(vf), "v"(hw))
#define FMIX_HI(acc, vf, hw) \
    asm("v_fma_mix_f32 %0, %1, %2, %0 op_sel:[0,1,0] op_sel_hi:[0,1,0]" \
        : "+v"(acc) : "v"(vf), "v"(hw))

// one edge's 8 FMIX ops
#define EDGE_FMIX(v, h) \
    FMIX_LO(a0, v, h.x); FMIX_HI(a1, v, h.x); \
    FMIX_LO(a2, v, h.y); FMIX_HI(a3, v, h.y); \
    FMIX_LO(a4, v, h.z); FMIX_HI(a5, v, h.z); \
    FMIX_LO(a6, v, h.w); FMIX_HI(a7, v, h.w)

// ---------- fused fp32 -> fp16 conversion into one concat arena [u|i|b] ----------
__global__ void cvt_feat(const float* __restrict__ su, const float* __restrict__ si,
                         const float* __restrict__ sb, __half2* __restrict__ dst,
                         long long pu, long long pi, long long pb) {
    long long tot = pu + pi + pb;
    long long stride = (long long)gridDim.x * blockDim.x;
    for (long long k = (long long)blockIdx.x * blockDim.x + threadIdx.x;
         k < tot; k += stride) {
        const float2* s;
        long long off;
        if (k < pu)           { s = (const float2*)su; off = k; }
        else if (k < pu + pi) { s = (const float2*)si; off = k - pu; }
        else                  { s = (const float2*)sb; off = k - pu - pi; }
        float2 v = s[off];
        dst[k] = __floats2half2_rn(v.x, v.y);
    }
}

// ---------- fused partition: LDS hist -> bucket reservation -> scatter ----------
// rec.x = (row_local << 20) | col, rec.y = bitcast(val)
__global__ __launch_bounds__(PART_T) void part_scatter4(
    const int* __restrict__ r0, const int* __restrict__ c0,
    const float* __restrict__ v0,
    const int* __restrict__ r1, const int* __restrict__ c1,
    const float* __restrict__ v1,
    const int* __restrict__ r2, const int* __restrict__ c2,
    const float* __restrict__ v2,
    int E0, int E1, int E2,
    int nb0, int nb1, int nb2,
    int* __restrict__ gcnt, int2* __restrict__ ev) {
    __shared__ int hist[MAX_NSB];        // phase1: counts; phase3: cursors
    int g = blockIdx.x / NPB, blk = blockIdx.x % NPB;
    const int* rows   = (g == 0) ? r0 : ((g == 1) ? r1 : r2);
    const int* cols   = (g == 0) ? c0 : ((g == 1) ? c1 : c2);
    const float* vals = (g == 0) ? v0 : ((g == 1) ? v1 : v2);
    int E     = (g == 0) ? E0  : ((g == 1) ? E1  : E2);
    int NSB   = (g == 0) ? nb0 : ((g == 1) ? nb1 : nb2);
    int bbase = (g == 0) ? 0   : ((g == 1) ? nb0 : nb0 + nb1);
    int chunk = (E + NPB - 1) / NPB;
    for (int b = threadIdx.x; b < NSB; b += PART_T) hist[b] = 0;
    __syncthreads();
    int s = blk * chunk, e = min(E, s + chunk);
    for (int i = s + threadIdx.x; i < e; i += PART_T)
        atomicAdd(&hist[rows[i] >> SB_SHIFT], 1);
    __syncthreads();
    // reserve a contiguous sub-range of each touched bucket's CAPB region
    for (int b = threadIdx.x; b < NSB; b += PART_T) {
        int h = hist[b];
        int off = h ? atomicAdd(&gcnt[bbase + b], h) : 0;
        hist[b] = off;                   // cursor
    }
    __syncthreads();
    for (int i = s + threadIdx.x; i < e; i += PART_T) {
        int r = rows[i];
        int lb = r >> SB_SHIFT;
        int p = atomicAdd(&hist[lb], 1);
        if (p < CAPB) {                  // overflow guard (statistically never)
            unsigned rec = ((unsigned)(r & (SB_ROWS - 1)) << PACK_SHIFT) | (unsigned)cols[i];
            ev[(size_t)(bbase + lb) * CAPB + p] =
                make_int2((int)rec, __float_as_int(vals[i]));
        }
    }
}

// ---------- per-bucket CSR finalize: register staging, in-place, emits row_be ----------
__global__ __launch_bounds__(FIN_T) void csr_finalize4(
    int2* __restrict__ ev, const int* __restrict__ gcnt,
    int nb0, int nb1, int nb2,
    int n0, int n1, int n2,
    int2* __restrict__ row_be) {
    __shared__ int cnt[SB_ROWS];         // 4 KB
    __shared__ int sc[SB_ROWS];          // 4 KB
    int gb = blockIdx.x, tid = threadIdx.x;
    int lb, n, rbase;
    if (gb < nb0)            { lb = gb;             n = n0; rbase = 0;       }
    else if (gb < nb0 + nb1) { lb = gb - nb0;       n = n1; rbase = n0;      }
    else                     { lb = gb - nb0 - nb1; n = n2; rbase = n0 + n1; }
    int base = gb * CAPB;                // <= 363*16384 ~ 5.9M, fits int
    int cntE = min(gcnt[gb], CAPB);      // <= 16384 = 16 * FIN_T
    cnt[tid] = 0;
    __syncthreads();
    // stage this thread's <=16 records in registers + histogram rows
    int2 regs[16];
    #pragma unroll
    for (int k = 0; k < 16; ++k) {
        int j = tid + k * FIN_T;
        if (j < cntE) {
            int2 r = ev[base + j];
            regs[k] = r;
            atomicAdd(&cnt[((unsigned)r.x) >> PACK_SHIFT], 1);
        }
    }
    __syncthreads();                     // all reads complete -> in-place safe
    // inclusive Hillis-Steele scan over 1024 rows
    sc[tid] = cnt[tid];
    __syncthreads();
    #pragma unroll
    for (int d = 1; d < SB_ROWS; d <<= 1) {
        int t = (tid >= d) ? sc[tid - d] : 0;
        __syncthreads();
        sc[tid] += t;
        __syncthreads();
    }
    int lo = lb << SB_SHIFT;
    int excl = sc[tid] - cnt[tid];
    if (lo + tid < n)
        row_be[rbase + lo + tid] = make_int2(base + excl, base + sc[tid]);
    cnt[tid] = excl;                     // reuse as write cursor (relative)
    __syncthreads();
    // write back row-sorted (strip row bits)
    #pragma unroll
    for (int k = 0; k < 16; ++k) {
        int j = tid + k * FIN_T;
        if (j < cntE) {
            int2 r = regs[k];
            int rl = (int)(((unsigned)r.x) >> PACK_SHIFT);
            int p = atomicAdd(&cnt[rl], 1);
            ev[base + p] = make_int2(r.x & ((1 << PACK_SHIFT) - 1), r.y);
        }
    }
}

// ---------- SpMM layer 1: 8 rows/wave x 8 lanes/row x 8 dims/lane, unroll 8 ----------
__global__ __launch_bounds__(256, 4) void spmm_l1_all(
    const int2* __restrict__ row_be, const int2* __restrict__ ev,
    const __half* __restrict__ feat,
    int n0, int n1, int n2,
    int thr1, int ao1, int bo1, int thr2, int ao2, int bo2,
    __half* __restrict__ f1) {
    int wid = (int)(((long long)blockIdx.x * blockDim.x + threadIdx.x) >> 6);
    int lane = threadIdx.x & 63;
    int oct = lane >> 3, sub = lane & 7;
    int w0 = (n0 + 7) >> 3, w1 = (n1 + 7) >> 3, w2 = (n2 + 7) >> 3;
    if (wid >= w0 + w1 + w2) return;
    int rg, n, rbase, thr, aoff, boff;
    if (wid < w0)           { rg = wid << 3;             n = n0; rbase = 0;       thr = 0x7fffffff; aoff = 0;   boff = 0;   }
    else if (wid < w0 + w1) { rg = (wid - w0) << 3;      n = n1; rbase = n0;      thr = thr1;       aoff = ao1; boff = bo1; }
    else                    { rg = (wid - w0 - w1) << 3; n = n2; rbase = n0 + n1; thr = thr2;       aoff = ao2; boff = bo2; }
    int r = rg + oct;
    bool rowok = r < n;
    int beg = 0, end = 0;
    if (rowok) { int2 be = row_be[rbase + r]; beg = be.x; end = be.y; }
    float a0 = 0.f, a1 = 0.f, a2 = 0.f, a3 = 0.f,
          a4 = 0.f, a5 = 0.f, a6 = 0.f, a7 = 0.f;
    int sb3 = sub << 3;
    for (int j = beg; __any(j < end); j += 8) {
        // phase 1: 8 ev loads (broadcast within octet)
        int2 e0 = ev[j],     e1 = ev[j + 1], e2 = ev[j + 2], e3 = ev[j + 3];
        int2 e4 = ev[j + 4], e5 = ev[j + 5], e6 = ev[j + 6], e7 = ev[j + 7];
        bool c0 = j < end,     c1 = j + 1 < end, c2 = j + 2 < end, c3 = j + 3 < end;
        bool c4 = j + 4 < end, c5 = j + 5 < end, c6 = j + 6 < end, c7 = j + 7 < end;
        float v0 = c0 ? __int_as_float(e0.y) : 0.0f;
        float v1 = c1 ? __int_as_float(e1.y) : 0.0f;
        float v2 = c2 ? __int_as_float(e2.y) : 0.0f;
        float v3 = c3 ? __int_as_float(e3.y) : 0.0f;
        float v4 = c4 ? __int_as_float(e4.y) : 0.0f;
        float v5 = c5 ? __int_as_float(e5.y) : 0.0f;
        float v6 = c6 ? __int_as_float(e6.y) : 0.0f;
        float v7 = c7 ? __int_as_float(e7.y) : 0.0f;
        // phase 2: 8 offsets
        unsigned o0 = c0 ? (((unsigned)(e0.x + ((e0.x < thr) ? aoff : boff)) << 6) + sb3) : 0u;
        unsigned o1 = c1 ? (((unsigned)(e1.x + ((e1.x < thr) ? aoff : boff)) << 6) + sb3) : 0u;
        unsigned o2 = c2 ? (((unsigned)(e2.x + ((e2.x < thr) ? aoff : boff)) << 6) + sb3) : 0u;
        unsigned o3 = c3 ? (((unsigned)(e3.x + ((e3.x < thr) ? aoff : boff)) << 6) + sb3) : 0u;
        unsigned o4 = c4 ? (((unsigned)(e4.x + ((e4.x < thr) ? aoff : boff)) << 6) + sb3) : 0u;
        unsigned o5 = c5 ? (((unsigned)(e5.x + ((e5.x < thr) ? aoff : boff)) << 6) + sb3) : 0u;
        unsigned o6 = c6 ? (((unsigned)(e6.x + ((e6.x < thr) ? aoff : boff)) << 6) + sb3) : 0u;
        unsigned o7 = c7 ? (((unsigned)(e7.x + ((e7.x < thr) ? aoff : boff)) << 6) + sb3) : 0u;
        // phase 3: 8 b128 gathers (all in flight)
        int4 h0 = *(const int4*)(feat + o0);
        int4 h1 = *(const int4*)(feat + o1);
        int4 h2 = *(const int4*)(feat + o2);
        int4 h3 = *(const int4*)(feat + o3);
        int4 h4 = *(const int4*)(feat + o4);
        int4 h5 = *(const int4*)(feat + o5);
        int4 h6 = *(const int4*)(feat + o6);
        int4 h7 = *(const int4*)(feat + o7);
        // phase 4: 64 FMIX
        EDGE_FMIX(v0, h0); EDGE_FMIX(v1, h1); EDGE_FMIX(v2, h2); EDGE_FMIX(v3, h3);
        EDGE_FMIX(v4, h4); EDGE_FMIX(v5, h5); EDGE_FMIX(v6, h6); EDGE_FMIX(v7, h7);
    }
    if (rowok) {
        __half2 p0 = __floats2half2_rn(a0 * F1_SCALE, a1 * F1_SCALE);
        __half2 p1 = __floats2half2_rn(a2 * F1_SCALE, a3 * F1_SCALE);
        __half2 p2 = __floats2half2_rn(a4 * F1_SCALE, a5 * F1_SCALE);
        __half2 p3 = __floats2half2_rn(a6 * F1_SCALE, a7 * F1_SCALE);
        int4 pk = make_int4(*(int*)&p0, *(int*)&p1, *(int*)&p2, *(int*)&p3);
        *(int4*)(f1 + (size_t)(rbase + r) * D + sb3) = pk;
    }
}

// ---------- SpMM layer 2 + epilogue: same 8x8x8 layout, unroll 8 ----------
__global__ __launch_bounds__(256, 4) void spmm_l2_all(
    const int2* __restrict__ row_be, const int2* __restrict__ ev,
    const __half* __restrict__ f1,
    const float* __restrict__ users, const float* __restrict__ items,
    const float* __restrict__ bundles,
    int n0, int n1, int n2,
    int U, int NI, int NB,
    float* __restrict__ out) {
    int wid = (int)(((long long)blockIdx.x * blockDim.x + threadIdx.x) >> 6);
    int lane = threadIdx.x & 63;
    int oct = lane >> 3, sub = lane & 7;
    int w0 = (n0 + 7) >> 3, w1 = (n1 + 7) >> 3, w2 = (n2 + 7) >> 3;
    if (wid >= w0 + w1 + w2) return;
    int rg, n, rbase, nA;
    const float *A32, *B32;
    long long offA, offB;
    if (wid < w0) {
        rg = wid << 3; n = n0; rbase = 0; nA = U; A32 = users; B32 = items;
        offA = 0; offB = 2LL * U + 2LL * NB;
    } else if (wid < w0 + w1) {
        rg = (wid - w0) << 3; n = n1; rbase = n0; nA = NB; A32 = bundles; B32 = items;
        offA = 2LL * U; offB = 2LL * U + 2LL * NB + NI;
    } else {
        rg = (wid - w0 - w1) << 3; n = n2; rbase = n0 + n1; nA = U; A32 = users; B32 = bundles;
        offA = (long long)U; offB = 2LL * U + NB;
    }
    int r = rg + oct;
    bool rowok = r < n;
    int beg = 0, end = 0;
    if (rowok) { int2 be = row_be[rbase + r]; beg = be.x; end = be.y; }
    const __half* f1g = f1 + (size_t)rbase * D;
    int sb3 = sub << 3;
    // hoist own-row f1 + x0 loads above the gather loop (latency hiding)
    int4 hx = rowok ? *(const int4*)(f1g + (size_t)r * D + sb3)
                    : make_int4(0, 0, 0, 0);
    const float* x0p = (r < nA) ? (A32 + (size_t)r * D) : (B32 + (size_t)(r - nA) * D);
    float4 x0a, x0b;
    if (rowok) {
        x0a = *(const float4*)(x0p + sb3);
        x0b = *(const float4*)(x0p + sb3 + 4);
    }
    float a0 = 0.f, a1 = 0.f, a2 = 0.f, a3 = 0.f,
          a4 = 0.f, a5 = 0.f, a6 = 0.f, a7 = 0.f;
    for (int j = beg; __any(j < end); j += 8) {
        int2 e0 = ev[j],     e1 = ev[j + 1], e2 = ev[j + 2], e3 = ev[j + 3];
        int2 e4 = ev[j + 4], e5 = ev[j + 5], e6 = ev[j + 6], e7 = ev[j + 7];
        bool c0 = j < end,     c1 = j + 1 < end, c2 = j + 2 < end, c3 = j + 3 < end;
        bool c4 = j + 4 < end, c5 = j + 5 < end, c6 = j + 6 < end, c7 = j + 7 < end;
        float v0 = c0 ? __int_as_float(e0.y) : 0.0f;
        float v1 = c1 ? __int_as_float(e1.y) : 0.0f;
        float v2 = c2 ? __int_as_float(e2.y) : 0.0f;
        float v3 = c3 ? __int_as_float(e3.y) : 0.0f;
        float v4 = c4 ? __int_as_float(e4.y) : 0.0f;
        float v5 = c5 ? __int_as_float(e5.y) : 0.0f;
        float v6 = c6 ? __int_as_float(e6.y) : 0.0f;
        float v7 = c7 ? __int_as_float(e7.y) : 0.0f;
        unsigned o0 = c0 ? (((unsigned)e0.x << 6) + sb3) : 0u;
        unsigned o1 = c1 ? (((unsigned)e1.x << 6) + sb3) : 0u;
        unsigned o2 = c2 ? (((unsigned)e2.x << 6) + sb3) : 0u;
        unsigned o3 = c3 ? (((unsigned)e3.x << 6) + sb3) : 0u;
        unsigned o4 = c4 ? (((unsigned)e4.x << 6) + sb3) : 0u;
        unsigned o5 = c5 ? (((unsigned)e5.x << 6) + sb3) : 0u;
        unsigned o6 = c6 ? (((unsigned)e6.x << 6) + sb3) : 0u;
        unsigned o7 = c7 ? (((unsigned)e7.x << 6) + sb3) : 0u;
        int4 h0 = *(const int4*)(f1g + o0);
        int4 h1 = *(const int4*)(f1g + o1);
        int4 h2 = *(const int4*)(f1g + o2);
        int4 h3 = *(const int4*)(f1g + o3);
        int4 h4 = *(const int4*)(f1g + o4);
        int4 h5 = *(const int4*)(f1g + o5);
        int4 h6 = *(const int4*)(f1g + o6);
        int4 h7 = *(const int4*)(f1g + o7);
        EDGE_FMIX(v0, h0); EDGE_FMIX(v1, h1); EDGE_FMIX(v2, h2); EDGE_FMIX(v3, h3);
        EDGE_FMIX(v4, h4); EDGE_FMIX(v5, h5); EDGE_FMIX(v6, h6); EDGE_FMIX(v7, h7);
    }
    // own-row f1 (scaled) -> floats; norms reduced across the octet (lane bits 0..2)
    float2 x01 = __half22float2(*(const __half2*)&hx.x);
    float2 x23 = __half22float2(*(const __half2*)&hx.y);
    float2 x45 = __half22float2(*(const __half2*)&hx.z);
    float2 x67 = __half22float2(*(const __half2*)&hx.w);
    float s1 = x01.x * x01.x + x01.y * x01.y + x23.x * x23.x + x23.y * x23.y
             + x45.x * x45.x + x45.y * x45.y + x67.x * x67.x + x67.y * x67.y;
    float s2 = a0 * a0 + a1 * a1 + a2 * a2 + a3 * a3
             + a4 * a4 + a5 * a5 + a6 * a6 + a7 * a7;
    #pragma unroll
    for (int m = 1; m <= 4; m <<= 1) {
        s1 += __shfl_xor(s1, m, 64);
        s2 += __shfl_xor(s2, m, 64);
    }
    float inv1 = 1.0f / fmaxf(sqrtf(s1), 1e-12f);
    float inv2 = 1.0f / fmaxf(sqrtf(s2), 1e-12f);
    long long orow = (r < nA) ? (offA + r) : (offB + (r - nA));
    if (rowok) {
        float4 ya, yb;
        ya.x = (x0a.x + x01.x * inv1 + a0 * inv2) * (1.0f / 3.0f);
        ya.y = (x0a.y + x01.y * inv1 + a1 * inv2) * (1.0f / 3.0f);
        ya.z = (x0a.z + x23.x * inv1 + a2 * inv2) * (1.0f / 3.0f);
        ya.w = (x0a.w + x23.y * inv1 + a3 * inv2) * (1.0f / 3.0f);
        yb.x = (x0b.x + x45.x * inv1 + a4 * inv2) * (1.0f / 3.0f);
        yb.y = (x0b.y + x45.y * inv1 + a5 * inv2) * (1.0f / 3.0f);
        yb.z = (x0b.z + x67.x * inv1 + a6 * inv2) * (1.0f / 3.0f);
        yb.w = (x0b.w + x67.y * inv1 + a7 * inv2) * (1.0f / 3.0f);
        float* op = out + orow * D + sb3;
        *(float4*)op = ya;
        *(float4*)(op + 4) = yb;
    }
}

extern "C" void kernel_launch(void* const* d_in, const int* in_sizes, int n_in,
                              void* d_out, int out_size, void* d_ws, size_t ws_size,
                              hipStream_t stream) {
    const float* users   = (const float*)d_in[0];
    const float* items   = (const float*)d_in[1];
    const float* bundles = (const float*)d_in[2];
    const float* ui_vals = (const float*)d_in[3];
    const float* bi_vals = (const float*)d_in[4];
    const float* ub_vals = (const float*)d_in[5];
    const int* ui_rows = (const int*)d_in[6];
    const int* ui_cols = (const int*)d_in[7];
    const int* bi_rows = (const int*)d_in[8];
    const int* bi_cols = (const int*)d_in[9];
    const int* ub_rows = (const int*)d_in[10];
    const int* ub_cols = (const int*)d_in[11];

    const int U  = in_sizes[0] / D;
    const int NI = in_sizes[1] / D;
    const int NB = in_sizes[2] / D;
    const int E_ui = in_sizes[3];
    const int E_bi = in_sizes[4];
    const int E_ub = in_sizes[5];

    float* out = (float*)d_out;

    const int n0 = U + NI, n1 = NB + NI, n2 = U + NB;      // per-graph row counts
    const int ntot = n0 + n1 + n2;                          // 340000
    const int nb0 = (n0 + SB_ROWS - 1) >> SB_SHIFT;         // 147
    const int nb1 = (n1 + SB_ROWS - 1) >> SB_SHIFT;         // 69
    const int nb2 = (n2 + SB_ROWS - 1) >> SB_SHIFT;         // 147
    const int nbt = nb0 + nb1 + nb2;                        // 363

    char* ws = (char*)d_ws;
    __half* feat16 = (__half*)ws; ws += (size_t)(U + NI + NB) * D * sizeof(__half); // 21.8 MB
    __half* f1     = (__half*)ws; ws += (size_t)ntot * D * sizeof(__half);          // 43.5 MB
    int2*  ev      = (int2*)ws;   ws += (size_t)nbt * CAPB * sizeof(int2);          // 47.6 MB
    int2*  row_be  = (int2*)ws;   ws += (size_t)ntot * sizeof(int2);                // 2.7 MB
    int*   gcnt    = (int*)ws;    ws += (size_t)nbt * sizeof(int);                  // 1.5 KB
    (void)ws_size;

    hipMemsetAsync(gcnt, 0, (size_t)nbt * sizeof(int), stream);

    // fp32 -> fp16 concat feature table
    cvt_feat<<<2048, 256, 0, stream>>>(users, items, bundles, (__half2*)feat16,
                                       (long long)U * (D / 2), (long long)NI * (D / 2),
                                       (long long)NB * (D / 2));

    // fused hist + reserve + scatter into per-bucket arena
    part_scatter4<<<3 * NPB, PART_T, 0, stream>>>(ui_rows, ui_cols, ui_vals,
                                                  bi_rows, bi_cols, bi_vals,
                                                  ub_rows, ub_cols, ub_vals,
                                                  E_ui, E_bi, E_ub, nb0, nb1, nb2,
                                                  gcnt, ev);
    csr_finalize4<<<nbt, FIN_T, 0, stream>>>(ev, gcnt, nb0, nb1, nb2,
                                             n0, n1, n2, row_be);

    // feature-space remap constants (col -> concat [u|i|b] index):
    // UI: identity. BI: bundles +U+NI (col<NB), items +U-NB. UB: users +0 (col<U), bundles +NI.
    const int w0 = (n0 + 7) >> 3, w1c = (n1 + 7) >> 3, w2c = (n2 + 7) >> 3;
    const int wtot = w0 + w1c + w2c;                  // 46250 waves
    const int rblocks = (wtot + 3) / 4;               // 4 waves per 256-block
    spmm_l1_all<<<rblocks, 256, 0, stream>>>(row_be, ev, feat16, n0, n1, n2,
                                             NB, U + NI, U - NB,
                                             U, 0, NI, f1);
    spmm_l2_all<<<rblocks, 256, 0, stream>>>(row_be, ev, f1,
                                             users, items, bundles,
                                             n0, n1, n2, U, NI, NB, out);
}

// Round 11
// 406.212 us; speedup vs baseline: 1.0118x; 1.0118x over previous
//
#include <hip/hip_runtime.h>
#include <hip/hip_fp16.h>

// DSS bundle propagation: 3 graphs x (2-layer SpMM + L2norm + average).
// R16: forced-MLP SpMM. R10 evidence: compiler re-serialized the 8-edge
// unroll (VGPR 44, not ~90) -> MLP ~4, l2 stuck at 95us, nothing saturated.
// Fix: gathers via inline-asm global_load_dwordx4 (volatile, independent,
// issue back-to-back; "=v" int4 outputs force distinct reg quads) +
// one s_waitcnt vmcnt(0) + sched_barrier(0) (guide rule #18) before the
// 64 FMIX. No min-waves bound -> occupancy floats. Partition stack
// (1024-row buckets NPB=170 + reg-staged finalize) unchanged from R14.
//
// Output rows: [UI_u(U) | UB_u(U) | BI_b(NB) | UB_b(NB) | UI_i(NI) | BI_i(NI)]

#define D 64
#define SB_SHIFT 10
#define SB_ROWS 1024
#define PACK_SHIFT 20      // rec.x = (row_local << 20) | col; col < 2^20
#define MAX_NSB 160        // >= ceil(150000/1024) = 147 (max per-graph)
#define NPB 170            // partition blocks per graph (510 total, 2/CU)
#define PART_T 1024        // threads per partition block
#define CAPB 16384         // arena slots per bucket (max mean ~14.6K, +15 sigma)
#define FIN_T 1024
#define F1_SCALE 4096.0f

// f32 acc += f32 v * f16 half of dword h (lo / hi). VOP3P v_fma_mix_f32.
#define FMIX_LO(acc, vf, hw) \
    asm("v_fma_mix_f32 %0, %1, %2, %0 op_sel:[0,0,0] op_sel_hi:[0,1,0]" \
        : "+v"(acc) : "v"(vf), "v"(hw))
#define FMIX_HI(acc, vf, hw) \
    asm("v_fma_mix_f32 %0, %1, %2, %0 op_sel:[0,1,0] op_sel_hi:[0,1,0]" \
        : "+v"(acc) : "v"(vf), "v"(hw))

// one edge's 8 FMIX ops
#define EDGE_FMIX(v, h) \
    FMIX_LO(a0, v, h.x); FMIX_HI(a1, v, h.x); \
    FMIX_LO(a2, v, h.y); FMIX_HI(a3, v, h.y); \
    FMIX_LO(a4, v, h.z); FMIX_HI(a5, v, h.z); \
    FMIX_LO(a6, v, h.w); FMIX_HI(a7, v, h.w)

// forced-in-flight 16B gather: issues immediately, completion deferred to
// the explicit s_waitcnt below. volatile => 8 of these stay back-to-back.
#define GLOAD(h, p) \
    asm volatile("global_load_dwordx4 %0, %1, off" : "=v"(h) : "v"(p))

// ---------- fused fp32 -> fp16 conversion into one concat arena [u|i|b] ----------
__global__ void cvt_feat(const float* __restrict__ su, const float* __restrict__ si,
                         const float* __restrict__ sb, __half2* __restrict__ dst,
                         long long pu, long long pi, long long pb) {
    long long tot = pu + pi + pb;
    long long stride = (long long)gridDim.x * blockDim.x;
    for (long long k = (long long)blockIdx.x * blockDim.x + threadIdx.x;
         k < tot; k += stride) {
        const float2* s;
        long long off;
        if (k < pu)           { s = (const float2*)su; off = k; }
        else if (k < pu + pi) { s = (const float2*)si; off = k - pu; }
        else                  { s = (const float2*)sb; off = k - pu - pi; }
        float2 v = s[off];
        dst[k] = __floats2half2_rn(v.x, v.y);
    }
}

// ---------- fused partition: LDS hist -> bucket reservation -> scatter ----------
// rec.x = (row_local << 20) | col, rec.y = bitcast(val)
__global__ __launch_bounds__(PART_T) void part_scatter4(
    const int* __restrict__ r0, const int* __restrict__ c0,
    const float* __restrict__ v0,
    const int* __restrict__ r1, const int* __restrict__ c1,
    const float* __restrict__ v1,
    const int* __restrict__ r2, const int* __restrict__ c2,
    const float* __restrict__ v2,
    int E0, int E1, int E2,
    int nb0, int nb1, int nb2,
    int* __restrict__ gcnt, int2* __restrict__ ev) {
    __shared__ int hist[MAX_NSB];        // phase1: counts; phase3: cursors
    int g = blockIdx.x / NPB, blk = blockIdx.x % NPB;
    const int* rows   = (g == 0) ? r0 : ((g == 1) ? r1 : r2);
    const int* cols   = (g == 0) ? c0 : ((g == 1) ? c1 : c2);
    const float* vals = (g == 0) ? v0 : ((g == 1) ? v1 : v2);
    int E     = (g == 0) ? E0  : ((g == 1) ? E1  : E2);
    int NSB   = (g == 0) ? nb0 : ((g == 1) ? nb1 : nb2);
    int bbase = (g == 0) ? 0   : ((g == 1) ? nb0 : nb0 + nb1);
    int chunk = (E + NPB - 1) / NPB;
    for (int b = threadIdx.x; b < NSB; b += PART_T) hist[b] = 0;
    __syncthreads();
    int s = blk * chunk, e = min(E, s + chunk);
    for (int i = s + threadIdx.x; i < e; i += PART_T)
        atomicAdd(&hist[rows[i] >> SB_SHIFT], 1);
    __syncthreads();
    // reserve a contiguous sub-range of each touched bucket's CAPB region
    for (int b = threadIdx.x; b < NSB; b += PART_T) {
        int h = hist[b];
        int off = h ? atomicAdd(&gcnt[bbase + b], h) : 0;
        hist[b] = off;                   // cursor
    }
    __syncthreads();
    for (int i = s + threadIdx.x; i < e; i += PART_T) {
        int r = rows[i];
        int lb = r >> SB_SHIFT;
        int p = atomicAdd(&hist[lb], 1);
        if (p < CAPB) {                  // overflow guard (statistically never)
            unsigned rec = ((unsigned)(r & (SB_ROWS - 1)) << PACK_SHIFT) | (unsigned)cols[i];
            ev[(size_t)(bbase + lb) * CAPB + p] =
                make_int2((int)rec, __float_as_int(vals[i]));
        }
    }
}

// ---------- per-bucket CSR finalize: register staging, in-place, emits row_be ----------
__global__ __launch_bounds__(FIN_T) void csr_finalize4(
    int2* __restrict__ ev, const int* __restrict__ gcnt,
    int nb0, int nb1, int nb2,
    int n0, int n1, int n2,
    int2* __restrict__ row_be) {
    __shared__ int cnt[SB_ROWS];         // 4 KB
    __shared__ int sc[SB_ROWS];          // 4 KB
    int gb = blockIdx.x, tid = threadIdx.x;
    int lb, n, rbase;
    if (gb < nb0)            { lb = gb;             n = n0; rbase = 0;       }
    else if (gb < nb0 + nb1) { lb = gb - nb0;       n = n1; rbase = n0;      }
    else                     { lb = gb - nb0 - nb1; n = n2; rbase = n0 + n1; }
    int base = gb * CAPB;                // <= 363*16384 ~ 5.9M, fits int
    int cntE = min(gcnt[gb], CAPB);      // <= 16384 = 16 * FIN_T
    cnt[tid] = 0;
    __syncthreads();
    // stage this thread's <=16 records in registers + histogram rows
    int2 regs[16];
    #pragma unroll
    for (int k = 0; k < 16; ++k) {
        int j = tid + k * FIN_T;
        if (j < cntE) {
            int2 r = ev[base + j];
            regs[k] = r;
            atomicAdd(&cnt[((unsigned)r.x) >> PACK_SHIFT], 1);
        }
    }
    __syncthreads();                     // all reads complete -> in-place safe
    // inclusive Hillis-Steele scan over 1024 rows
    sc[tid] = cnt[tid];
    __syncthreads();
    #pragma unroll
    for (int d = 1; d < SB_ROWS; d <<= 1) {
        int t = (tid >= d) ? sc[tid - d] : 0;
        __syncthreads();
        sc[tid] += t;
        __syncthreads();
    }
    int lo = lb << SB_SHIFT;
    int excl = sc[tid] - cnt[tid];
    if (lo + tid < n)
        row_be[rbase + lo + tid] = make_int2(base + excl, base + sc[tid]);
    cnt[tid] = excl;                     // reuse as write cursor (relative)
    __syncthreads();
    // write back row-sorted (strip row bits)
    #pragma unroll
    for (int k = 0; k < 16; ++k) {
        int j = tid + k * FIN_T;
        if (j < cntE) {
            int2 r = regs[k];
            int rl = (int)(((unsigned)r.x) >> PACK_SHIFT);
            int p = atomicAdd(&cnt[rl], 1);
            ev[base + p] = make_int2(r.x & ((1 << PACK_SHIFT) - 1), r.y);
        }
    }
}

// ---------- SpMM layer 1: 8 rows/wave x 8 lanes/row x 8 dims/lane, asm-MLP 8 ----------
__global__ __launch_bounds__(256) void spmm_l1_all(
    const int2* __restrict__ row_be, const int2* __restrict__ ev,
    const __half* __restrict__ feat,
    int n0, int n1, int n2,
    int thr1, int ao1, int bo1, int thr2, int ao2, int bo2,
    __half* __restrict__ f1) {
    int wid = (int)(((long long)blockIdx.x * blockDim.x + threadIdx.x) >> 6);
    int lane = threadIdx.x & 63;
    int oct = lane >> 3, sub = lane & 7;
    int w0 = (n0 + 7) >> 3, w1 = (n1 + 7) >> 3, w2 = (n2 + 7) >> 3;
    if (wid >= w0 + w1 + w2) return;
    int rg, n, rbase, thr, aoff, boff;
    if (wid < w0)           { rg = wid << 3;             n = n0; rbase = 0;       thr = 0x7fffffff; aoff = 0;   boff = 0;   }
    else if (wid < w0 + w1) { rg = (wid - w0) << 3;      n = n1; rbase = n0;      thr = thr1;       aoff = ao1; boff = bo1; }
    else                    { rg = (wid - w0 - w1) << 3; n = n2; rbase = n0 + n1; thr = thr2;       aoff = ao2; boff = bo2; }
    int r = rg + oct;
    bool rowok = r < n;
    int beg = 0, end = 0;
    if (rowok) { int2 be = row_be[rbase + r]; beg = be.x; end = be.y; }
    float a0 = 0.f, a1 = 0.f, a2 = 0.f, a3 = 0.f,
          a4 = 0.f, a5 = 0.f, a6 = 0.f, a7 = 0.f;
    int sb3 = sub << 3;
    for (int j = beg; __any(j < end); j += 8) {
        int2 e0 = ev[j],     e1 = ev[j + 1], e2 = ev[j + 2], e3 = ev[j + 3];
        int2 e4 = ev[j + 4], e5 = ev[j + 5], e6 = ev[j + 6], e7 = ev[j + 7];
        bool c0 = j < end,     c1 = j + 1 < end, c2 = j + 2 < end, c3 = j + 3 < end;
        bool c4 = j + 4 < end, c5 = j + 5 < end, c6 = j + 6 < end, c7 = j + 7 < end;
        float v0 = c0 ? __int_as_float(e0.y) : 0.0f;
        float v1 = c1 ? __int_as_float(e1.y) : 0.0f;
        float v2 = c2 ? __int_as_float(e2.y) : 0.0f;
        float v3 = c3 ? __int_as_float(e3.y) : 0.0f;
        float v4 = c4 ? __int_as_float(e4.y) : 0.0f;
        float v5 = c5 ? __int_as_float(e5.y) : 0.0f;
        float v6 = c6 ? __int_as_float(e6.y) : 0.0f;
        float v7 = c7 ? __int_as_float(e7.y) : 0.0f;
        unsigned o0 = c0 ? (((unsigned)(e0.x + ((e0.x < thr) ? aoff : boff)) << 6) + sb3) : 0u;
        unsigned o1 = c1 ? (((unsigned)(e1.x + ((e1.x < thr) ? aoff : boff)) << 6) + sb3) : 0u;
        unsigned o2 = c2 ? (((unsigned)(e2.x + ((e2.x < thr) ? aoff : boff)) << 6) + sb3) : 0u;
        unsigned o3 = c3 ? (((unsigned)(e3.x + ((e3.x < thr) ? aoff : boff)) << 6) + sb3) : 0u;
        unsigned o4 = c4 ? (((unsigned)(e4.x + ((e4.x < thr) ? aoff : boff)) << 6) + sb3) : 0u;
        unsigned o5 = c5 ? (((unsigned)(e5.x + ((e5.x < thr) ? aoff : boff)) << 6) + sb3) : 0u;
        unsigned o6 = c6 ? (((unsigned)(e6.x + ((e6.x < thr) ? aoff : boff)) << 6) + sb3) : 0u;
        unsigned o7 = c7 ? (((unsigned)(e7.x + ((e7.x < thr) ? aoff : boff)) << 6) + sb3) : 0u;
        int4 h0, h1, h2, h3, h4, h5, h6, h7;
        GLOAD(h0, (const void*)(feat + o0));
        GLOAD(h1, (const void*)(feat + o1));
        GLOAD(h2, (const void*)(feat + o2));
        GLOAD(h3, (const void*)(feat + o3));
        GLOAD(h4, (const void*)(feat + o4));
        GLOAD(h5, (const void*)(feat + o5));
        GLOAD(h6, (const void*)(feat + o6));
        GLOAD(h7, (const void*)(feat + o7));
        asm volatile("s_waitcnt vmcnt(0)" ::: "memory");
        __builtin_amdgcn_sched_barrier(0);
        EDGE_FMIX(v0, h0); EDGE_FMIX(v1, h1); EDGE_FMIX(v2, h2); EDGE_FMIX(v3, h3);
        EDGE_FMIX(v4, h4); EDGE_FMIX(v5, h5); EDGE_FMIX(v6, h6); EDGE_FMIX(v7, h7);
    }
    if (rowok) {
        __half2 p0 = __floats2half2_rn(a0 * F1_SCALE, a1 * F1_SCALE);
        __half2 p1 = __floats2half2_rn(a2 * F1_SCALE, a3 * F1_SCALE);
        __half2 p2 = __floats2half2_rn(a4 * F1_SCALE, a5 * F1_SCALE);
        __half2 p3 = __floats2half2_rn(a6 * F1_SCALE, a7 * F1_SCALE);
        int4 pk = make_int4(*(int*)&p0, *(int*)&p1, *(int*)&p2, *(int*)&p3);
        *(int4*)(f1 + (size_t)(rbase + r) * D + sb3) = pk;
    }
}

// ---------- SpMM layer 2 + epilogue: same 8x8x8 layout, asm-MLP 8 ----------
__global__ __launch_bounds__(256) void spmm_l2_all(
    const int2* __restrict__ row_be, const int2* __restrict__ ev,
    const __half* __restrict__ f1,
    const float* __restrict__ users, const float* __restrict__ items,
    const float* __restrict__ bundles,
    int n0, int n1, int n2,
    int U, int NI, int NB,
    float* __restrict__ out) {
    int wid = (int)(((long long)blockIdx.x * blockDim.x + threadIdx.x) >> 6);
    int lane = threadIdx.x & 63;
    int oct = lane >> 3, sub = lane & 7;
    int w0 = (n0 + 7) >> 3, w1 = (n1 + 7) >> 3, w2 = (n2 + 7) >> 3;
    if (wid >= w0 + w1 + w2) return;
    int rg, n, rbase, nA;
    const float *A32, *B32;
    long long offA, offB;
    if (wid < w0) {
        rg = wid << 3; n = n0; rbase = 0; nA = U; A32 = users; B32 = items;
        offA = 0; offB = 2LL * U + 2LL * NB;
    } else if (wid < w0 + w1) {
        rg = (wid - w0) << 3; n = n1; rbase = n0; nA = NB; A32 = bundles; B32 = items;
        offA = 2LL * U; offB = 2LL * U + 2LL * NB + NI;
    } else {
        rg = (wid - w0 - w1) << 3; n = n2; rbase = n0 + n1; nA = U; A32 = users; B32 = bundles;
        offA = (long long)U; offB = 2LL * U + NB;
    }
    int r = rg + oct;
    bool rowok = r < n;
    int beg = 0, end = 0;
    if (rowok) { int2 be = row_be[rbase + r]; beg = be.x; end = be.y; }
    const __half* f1g = f1 + (size_t)rbase * D;
    int sb3 = sub << 3;
    // hoist own-row f1 + x0 loads above the gather loop (latency hiding)
    int4 hx = rowok ? *(const int4*)(f1g + (size_t)r * D + sb3)
                    : make_int4(0, 0, 0, 0);
    const float* x0p = (r < nA) ? (A32 + (size_t)r * D) : (B32 + (size_t)(r - nA) * D);
    float4 x0a, x0b;
    if (rowok) {
        x0a = *(const float4*)(x0p + sb3);
        x0b = *(const float4*)(x0p + sb3 + 4);
    }
    float a0 = 0.f, a1 = 0.f, a2 = 0.f, a3 = 0.f,
          a4 = 0.f, a5 = 0.f, a6 = 0.f, a7 = 0.f;
    for (int j = beg; __any(j < end); j += 8) {
        int2 e0 = ev[j],     e1 = ev[j + 1], e2 = ev[j + 2], e3 = ev[j + 3];
        int2 e4 = ev[j + 4], e5 = ev[j + 5], e6 = ev[j + 6], e7 = ev[j + 7];
        bool c0 = j < end,     c1 = j + 1 < end, c2 = j + 2 < end, c3 = j + 3 < end;
        bool c4 = j + 4 < end, c5 = j + 5 < end, c6 = j + 6 < end, c7 = j + 7 < end;
        float v0 = c0 ? __int_as_float(e0.y) : 0.0f;
        float v1 = c1 ? __int_as_float(e1.y) : 0.0f;
        float v2 = c2 ? __int_as_float(e2.y) : 0.0f;
        float v3 = c3 ? __int_as_float(e3.y) : 0.0f;
        float v4 = c4 ? __int_as_float(e4.y) : 0.0f;
        float v5 = c5 ? __int_as_float(e5.y) : 0.0f;
        float v6 = c6 ? __int_as_float(e6.y) : 0.0f;
        float v7 = c7 ? __int_as_float(e7.y) : 0.0f;
        unsigned o0 = c0 ? (((unsigned)e0.x << 6) + sb3) : 0u;
        unsigned o1 = c1 ? (((unsigned)e1.x << 6) + sb3) : 0u;
        unsigned o2 = c2 ? (((unsigned)e2.x << 6) + sb3) : 0u;
        unsigned o3 = c3 ? (((unsigned)e3.x << 6) + sb3) : 0u;
        unsigned o4 = c4 ? (((unsigned)e4.x << 6) + sb3) : 0u;
        unsigned o5 = c5 ? (((unsigned)e5.x << 6) + sb3) : 0u;
        unsigned o6 = c6 ? (((unsigned)e6.x << 6) + sb3) : 0u;
        unsigned o7 = c7 ? (((unsigned)e7.x << 6) + sb3) : 0u;
        int4 h0, h1, h2, h3, h4, h5, h6, h7;
        GLOAD(h0, (const void*)(f1g + o0));
        GLOAD(h1, (const void*)(f1g + o1));
        GLOAD(h2, (const void*)(f1g + o2));
        GLOAD(h3, (const void*)(f1g + o3));
        GLOAD(h4, (const void*)(f1g + o4));
        GLOAD(h5, (const void*)(f1g + o5));
        GLOAD(h6, (const void*)(f1g + o6));
        GLOAD(h7, (const void*)(f1g + o7));
        asm volatile("s_waitcnt vmcnt(0)" ::: "memory");
        __builtin_amdgcn_sched_barrier(0);
        EDGE_FMIX(v0, h0); EDGE_FMIX(v1, h1); EDGE_FMIX(v2, h2); EDGE_FMIX(v3, h3);
        EDGE_FMIX(v4, h4); EDGE_FMIX(v5, h5); EDGE_FMIX(v6, h6); EDGE_FMIX(v7, h7);
    }
    // own-row f1 (scaled) -> floats; norms reduced across the octet (lane bits 0..2)
    float2 x01 = __half22float2(*(const __half2*)&hx.x);
    float2 x23 = __half22float2(*(const __half2*)&hx.y);
    float2 x45 = __half22float2(*(const __half2*)&hx.z);
    float2 x67 = __half22float2(*(const __half2*)&hx.w);
    float s1 = x01.x * x01.x + x01.y * x01.y + x23.x * x23.x + x23.y * x23.y
             + x45.x * x45.x + x45.y * x45.y + x67.x * x67.x + x67.y * x67.y;
    float s2 = a0 * a0 + a1 * a1 + a2 * a2 + a3 * a3
             + a4 * a4 + a5 * a5 + a6 * a6 + a7 * a7;
    #pragma unroll
    for (int m = 1; m <= 4; m <<= 1) {
        s1 += __shfl_xor(s1, m, 64);
        s2 += __shfl_xor(s2, m, 64);
    }
    float inv1 = 1.0f / fmaxf(sqrtf(s1), 1e-12f);
    float inv2 = 1.0f / fmaxf(sqrtf(s2), 1e-12f);
    long long orow = (r < nA) ? (offA + r) : (offB + (r - nA));
    if (rowok) {
        float4 ya, yb;
        ya.x = (x0a.x + x01.x * inv1 + a0 * inv2) * (1.0f / 3.0f);
        ya.y = (x0a.y + x01.y * inv1 + a1 * inv2) * (1.0f / 3.0f);
        ya.z = (x0a.z + x23.x * inv1 + a2 * inv2) * (1.0f / 3.0f);
        ya.w = (x0a.w + x23.y * inv1 + a3 * inv2) * (1.0f / 3.0f);
        yb.x = (x0b.x + x45.x * inv1 + a4 * inv2) * (1.0f / 3.0f);
        yb.y = (x0b.y + x45.y * inv1 + a5 * inv2) * (1.0f / 3.0f);
        yb.z = (x0b.z + x67.x * inv1 + a6 * inv2) * (1.0f / 3.0f);
        yb.w = (x0b.w + x67.y * inv1 + a7 * inv2) * (1.0f / 3.0f);
        float* op = out + orow * D + sb3;
        *(float4*)op = ya;
        *(float4*)(op + 4) = yb;
    }
}

extern "C" void kernel_launch(void* const* d_in, const int* in_sizes, int n_in,
                              void* d_out, int out_size, void* d_ws, size_t ws_size,
                              hipStream_t stream) {
    const float* users   = (const float*)d_in[0];
    const float* items   = (const float*)d_in[1];
    const float* bundles = (const float*)d_in[2];
    const float* ui_vals = (const float*)d_in[3];
    const float* bi_vals = (const float*)d_in[4];
    const float* ub_vals = (const float*)d_in[5];
    const int* ui_rows = (const int*)d_in[6];
    const int* ui_cols = (const int*)d_in[7];
    const int* bi_rows = (const int*)d_in[8];
    const int* bi_cols = (const int*)d_in[9];
    const int* ub_rows = (const int*)d_in[10];
    const int* ub_cols = (const int*)d_in[11];

    const int U  = in_sizes[0] / D;
    const int NI = in_sizes[1] / D;
    const int NB = in_sizes[2] / D;
    const int E_ui = in_sizes[3];
    const int E_bi = in_sizes[4];
    const int E_ub = in_sizes[5];

    float* out = (float*)d_out;

    const int n0 = U + NI, n1 = NB + NI, n2 = U + NB;      // per-graph row counts
    const int ntot = n0 + n1 + n2;                          // 340000
    const int nb0 = (n0 + SB_ROWS - 1) >> SB_SHIFT;         // 147
    const int nb1 = (n1 + SB_ROWS - 1) >> SB_SHIFT;         // 69
    const int nb2 = (n2 + SB_ROWS - 1) >> SB_SHIFT;         // 147
    const int nbt = nb0 + nb1 + nb2;                        // 363

    char* ws = (char*)d_ws;
    __half* feat16 = (__half*)ws; ws += (size_t)(U + NI + NB) * D * sizeof(__half); // 21.8 MB
    __half* f1     = (__half*)ws; ws += (size_t)ntot * D * sizeof(__half);          // 43.5 MB
    int2*  ev      = (int2*)ws;   ws += (size_t)nbt * CAPB * sizeof(int2);          // 47.6 MB
    int2*  row_be  = (int2*)ws;   ws += (size_t)ntot * sizeof(int2);                // 2.7 MB
    int*   gcnt    = (int*)ws;    ws += (size_t)nbt * sizeof(int);                  // 1.5 KB
    (void)ws_size;

    hipMemsetAsync(gcnt, 0, (size_t)nbt * sizeof(int), stream);

    // fp32 -> fp16 concat feature table
    cvt_feat<<<2048, 256, 0, stream>>>(users, items, bundles, (__half2*)feat16,
                                       (long long)U * (D / 2), (long long)NI * (D / 2),
                                       (long long)NB * (D / 2));

    // fused hist + reserve + scatter into per-bucket arena
    part_scatter4<<<3 * NPB, PART_T, 0, stream>>>(ui_rows, ui_cols, ui_vals,
                                                  bi_rows, bi_cols, bi_vals,
                                                  ub_rows, ub_cols, ub_vals,
                                                  E_ui, E_bi, E_ub, nb0, nb1, nb2,
                                                  gcnt, ev);
    csr_finalize4<<<nbt, FIN_T, 0, stream>>>(ev, gcnt, nb0, nb1, nb2,
                                             n0, n1, n2, row_be);

    // feature-space remap constants (col -> concat [u|i|b] index):
    // UI: identity. BI: bundles +U+NI (col<NB), items +U-NB. UB: users +0 (col<U), bundles +NI.
    const int w0 = (n0 + 7) >> 3, w1c = (n1 + 7) >> 3, w2c = (n2 + 7) >> 3;
    const int wtot = w0 + w1c + w2c;                  // 46250 waves
    const int rblocks = (wtot + 3) / 4;               // 4 waves per 256-block
    spmm_l1_all<<<rblocks, 256, 0, stream>>>(row_be, ev, feat16, n0, n1, n2,
                                             NB, U + NI, U - NB,
                                             U, 0, NI, f1);
    spmm_l2_all<<<rblocks, 256, 0, stream>>>(row_be, ev, f1,
                                             users, items, bundles,
                                             n0, n1, n2, U, NI, NB, out);
}

// Round 12
// 405.427 us; speedup vs baseline: 1.0138x; 1.0019x over previous
//
#include <hip/hip_runtime.h>
#include <hip/hip_fp16.h>

// DSS bundle propagation: 3 graphs x (2-layer SpMM + L2norm + average).
// R17: 16-edge gather batches. R11 evidence: wait-all-then-FMIX alternation
// (8 gathers, vmcnt(0), 64 FMIX) leaves zero memory in flight during compute;
// HBM 50% / VALU 40% / occ 45% -- nothing saturated, in-flight ~112 lines/CU
// barely meets Little's law. Short rows (mean deg ~13) make per-wave
// pipelining all-prologue, so instead: 16 forced-asm gathers per batch
// (~89% of rows done in ONE batch; VGPR ~110-130 -> 4-5 waves/SIMD ->
// ~260-320 lines in flight/CU, 2.5x). Also: l2's own-row x0 now read from
// feat16 (same thr/aoff/boff remap as l1) -- fetch -43 MB, less L3 pressure.
// Partition stack (1024-row buckets NPB=170 + reg-staged finalize) unchanged.
//
// Output rows: [UI_u(U) | UB_u(U) | BI_b(NB) | UB_b(NB) | UI_i(NI) | BI_i(NI)]

#define D 64
#define SB_SHIFT 10
#define SB_ROWS 1024
#define PACK_SHIFT 20      // rec.x = (row_local << 20) | col; col < 2^20
#define MAX_NSB 160        // >= ceil(150000/1024) = 147 (max per-graph)
#define NPB 170            // partition blocks per graph (510 total, 2/CU)
#define PART_T 1024        // threads per partition block
#define CAPB 16384         // arena slots per bucket (max mean ~14.6K, +15 sigma)
#define FIN_T 1024
#define UNR 16             // edges per gather batch per octet
#define F1_SCALE 4096.0f

// f32 acc += f32 v * f16 half of dword h (lo / hi). VOP3P v_fma_mix_f32.
#define FMIX_LO(acc, vf, hw) \
    asm("v_fma_mix_f32 %0, %1, %2, %0 op_sel:[0,0,0] op_sel_hi:[0,1,0]" \
        : "+v"(acc) : "v"(vf), "v"(hw))
#define FMIX_HI(acc, vf, hw) \
    asm("v_fma_mix_f32 %0, %1, %2, %0 op_sel:[0,1,0] op_sel_hi:[0,1,0]" \
        : "+v"(acc) : "v"(vf), "v"(hw))

// one edge's 8 FMIX ops
#define EDGE_FMIX(v, h) \
    FMIX_LO(a0, v, h.x); FMIX_HI(a1, v, h.x); \
    FMIX_LO(a2, v, h.y); FMIX_HI(a3, v, h.y); \
    FMIX_LO(a4, v, h.z); FMIX_HI(a5, v, h.z); \
    FMIX_LO(a6, v, h.w); FMIX_HI(a7, v, h.w)

// forced-in-flight 16B gather: issues immediately; completion deferred to
// the explicit s_waitcnt. volatile => the 16 stay back-to-back.
#define GLOAD(h, p) \
    asm volatile("global_load_dwordx4 %0, %1, off" : "=v"(h) : "v"(p))

// ---------- fused fp32 -> fp16 conversion into one concat arena [u|i|b] ----------
__global__ void cvt_feat(const float* __restrict__ su, const float* __restrict__ si,
                         const float* __restrict__ sb, __half2* __restrict__ dst,
                         long long pu, long long pi, long long pb) {
    long long tot = pu + pi + pb;
    long long stride = (long long)gridDim.x * blockDim.x;
    for (long long k = (long long)blockIdx.x * blockDim.x + threadIdx.x;
         k < tot; k += stride) {
        const float2* s;
        long long off;
        if (k < pu)           { s = (const float2*)su; off = k; }
        else if (k < pu + pi) { s = (const float2*)si; off = k - pu; }
        else                  { s = (const float2*)sb; off = k - pu - pi; }
        float2 v = s[off];
        dst[k] = __floats2half2_rn(v.x, v.y);
    }
}

// ---------- fused partition: LDS hist -> bucket reservation -> scatter ----------
// rec.x = (row_local << 20) | col, rec.y = bitcast(val)
__global__ __launch_bounds__(PART_T) void part_scatter4(
    const int* __restrict__ r0, const int* __restrict__ c0,
    const float* __restrict__ v0,
    const int* __restrict__ r1, const int* __restrict__ c1,
    const float* __restrict__ v1,
    const int* __restrict__ r2, const int* __restrict__ c2,
    const float* __restrict__ v2,
    int E0, int E1, int E2,
    int nb0, int nb1, int nb2,
    int* __restrict__ gcnt, int2* __restrict__ ev) {
    __shared__ int hist[MAX_NSB];        // phase1: counts; phase3: cursors
    int g = blockIdx.x / NPB, blk = blockIdx.x % NPB;
    const int* rows   = (g == 0) ? r0 : ((g == 1) ? r1 : r2);
    const int* cols   = (g == 0) ? c0 : ((g == 1) ? c1 : c2);
    const float* vals = (g == 0) ? v0 : ((g == 1) ? v1 : v2);
    int E     = (g == 0) ? E0  : ((g == 1) ? E1  : E2);
    int NSB   = (g == 0) ? nb0 : ((g == 1) ? nb1 : nb2);
    int bbase = (g == 0) ? 0   : ((g == 1) ? nb0 : nb0 + nb1);
    int chunk = (E + NPB - 1) / NPB;
    for (int b = threadIdx.x; b < NSB; b += PART_T) hist[b] = 0;
    __syncthreads();
    int s = blk * chunk, e = min(E, s + chunk);
    for (int i = s + threadIdx.x; i < e; i += PART_T)
        atomicAdd(&hist[rows[i] >> SB_SHIFT], 1);
    __syncthreads();
    // reserve a contiguous sub-range of each touched bucket's CAPB region
    for (int b = threadIdx.x; b < NSB; b += PART_T) {
        int h = hist[b];
        int off = h ? atomicAdd(&gcnt[bbase + b], h) : 0;
        hist[b] = off;                   // cursor
    }
    __syncthreads();
    for (int i = s + threadIdx.x; i < e; i += PART_T) {
        int r = rows[i];
        int lb = r >> SB_SHIFT;
        int p = atomicAdd(&hist[lb], 1);
        if (p < CAPB) {                  // overflow guard (statistically never)
            unsigned rec = ((unsigned)(r & (SB_ROWS - 1)) << PACK_SHIFT) | (unsigned)cols[i];
            ev[(size_t)(bbase + lb) * CAPB + p] =
                make_int2((int)rec, __float_as_int(vals[i]));
        }
    }
}

// ---------- per-bucket CSR finalize: register staging, in-place, emits row_be ----------
__global__ __launch_bounds__(FIN_T) void csr_finalize4(
    int2* __restrict__ ev, const int* __restrict__ gcnt,
    int nb0, int nb1, int nb2,
    int n0, int n1, int n2,
    int2* __restrict__ row_be) {
    __shared__ int cnt[SB_ROWS];         // 4 KB
    __shared__ int sc[SB_ROWS];          // 4 KB
    int gb = blockIdx.x, tid = threadIdx.x;
    int lb, n, rbase;
    if (gb < nb0)            { lb = gb;             n = n0; rbase = 0;       }
    else if (gb < nb0 + nb1) { lb = gb - nb0;       n = n1; rbase = n0;      }
    else                     { lb = gb - nb0 - nb1; n = n2; rbase = n0 + n1; }
    int base = gb * CAPB;                // <= 363*16384 ~ 5.9M, fits int
    int cntE = min(gcnt[gb], CAPB);      // <= 16384 = 16 * FIN_T
    cnt[tid] = 0;
    __syncthreads();
    // stage this thread's <=16 records in registers + histogram rows
    int2 regs[16];
    #pragma unroll
    for (int k = 0; k < 16; ++k) {
        int j = tid + k * FIN_T;
        if (j < cntE) {
            int2 r = ev[base + j];
            regs[k] = r;
            atomicAdd(&cnt[((unsigned)r.x) >> PACK_SHIFT], 1);
        }
    }
    __syncthreads();                     // all reads complete -> in-place safe
    // inclusive Hillis-Steele scan over 1024 rows
    sc[tid] = cnt[tid];
    __syncthreads();
    #pragma unroll
    for (int d = 1; d < SB_ROWS; d <<= 1) {
        int t = (tid >= d) ? sc[tid - d] : 0;
        __syncthreads();
        sc[tid] += t;
        __syncthreads();
    }
    int lo = lb << SB_SHIFT;
    int excl = sc[tid] - cnt[tid];
    if (lo + tid < n)
        row_be[rbase + lo + tid] = make_int2(base + excl, base + sc[tid]);
    cnt[tid] = excl;                     // reuse as write cursor (relative)
    __syncthreads();
    // write back row-sorted (strip row bits)
    #pragma unroll
    for (int k = 0; k < 16; ++k) {
        int j = tid + k * FIN_T;
        if (j < cntE) {
            int2 r = regs[k];
            int rl = (int)(((unsigned)r.x) >> PACK_SHIFT);
            int p = atomicAdd(&cnt[rl], 1);
            ev[base + p] = make_int2(r.x & ((1 << PACK_SHIFT) - 1), r.y);
        }
    }
}

// ---------- SpMM layer 1: 8 rows/wave x 8 lanes/row, 16-edge asm batches ----------
__global__ __launch_bounds__(256) void spmm_l1_all(
    const int2* __restrict__ row_be, const int2* __restrict__ ev,
    const __half* __restrict__ feat,
    int n0, int n1, int n2,
    int thr1, int ao1, int bo1, int thr2, int ao2, int bo2,
    __half* __restrict__ f1) {
    int wid = (int)(((long long)blockIdx.x * blockDim.x + threadIdx.x) >> 6);
    int lane = threadIdx.x & 63;
    int oct = lane >> 3, sub = lane & 7;
    int w0 = (n0 + 7) >> 3, w1 = (n1 + 7) >> 3, w2 = (n2 + 7) >> 3;
    if (wid >= w0 + w1 + w2) return;
    int rg, n, rbase, thr, aoff, boff;
    if (wid < w0)           { rg = wid << 3;             n = n0; rbase = 0;       thr = 0x7fffffff; aoff = 0;   boff = 0;   }
    else if (wid < w0 + w1) { rg = (wid - w0) << 3;      n = n1; rbase = n0;      thr = thr1;       aoff = ao1; boff = bo1; }
    else                    { rg = (wid - w0 - w1) << 3; n = n2; rbase = n0 + n1; thr = thr2;       aoff = ao2; boff = bo2; }
    int r = rg + oct;
    bool rowok = r < n;
    int beg = 0, end = 0;
    if (rowok) { int2 be = row_be[rbase + r]; beg = be.x; end = be.y; }
    float a0 = 0.f, a1 = 0.f, a2 = 0.f, a3 = 0.f,
          a4 = 0.f, a5 = 0.f, a6 = 0.f, a7 = 0.f;
    int sb3 = sub << 3;
    for (int j = beg; __any(j < end); j += UNR) {
        float v[UNR];
        unsigned o[UNR];
        int4 h[UNR];
        #pragma unroll
        for (int k = 0; k < UNR; ++k) {
            int2 ek = ev[j + k];
            bool c = (j + k) < end;
            v[k] = c ? __int_as_float(ek.y) : 0.0f;
            o[k] = c ? (((unsigned)(ek.x + ((ek.x < thr) ? aoff : boff)) << 6) + sb3) : 0u;
        }
        #pragma unroll
        for (int k = 0; k < UNR; ++k) GLOAD(h[k], (const void*)(feat + o[k]));
        asm volatile("s_waitcnt vmcnt(0)" ::: "memory");
        __builtin_amdgcn_sched_barrier(0);
        #pragma unroll
        for (int k = 0; k < UNR; ++k) { EDGE_FMIX(v[k], h[k]); }
    }
    if (rowok) {
        __half2 p0 = __floats2half2_rn(a0 * F1_SCALE, a1 * F1_SCALE);
        __half2 p1 = __floats2half2_rn(a2 * F1_SCALE, a3 * F1_SCALE);
        __half2 p2 = __floats2half2_rn(a4 * F1_SCALE, a5 * F1_SCALE);
        __half2 p3 = __floats2half2_rn(a6 * F1_SCALE, a7 * F1_SCALE);
        int4 pk = make_int4(*(int*)&p0, *(int*)&p1, *(int*)&p2, *(int*)&p3);
        *(int4*)(f1 + (size_t)(rbase + r) * D + sb3) = pk;
    }
}

// ---------- SpMM layer 2 + epilogue: 16-edge asm batches, x0 from feat16 ----------
__global__ __launch_bounds__(256) void spmm_l2_all(
    const int2* __restrict__ row_be, const int2* __restrict__ ev,
    const __half* __restrict__ f1, const __half* __restrict__ feat,
    int n0, int n1, int n2,
    int U, int NI, int NB,
    int thr1, int ao1, int bo1, int thr2, int ao2, int bo2,
    float* __restrict__ out) {
    int wid = (int)(((long long)blockIdx.x * blockDim.x + threadIdx.x) >> 6);
    int lane = threadIdx.x & 63;
    int oct = lane >> 3, sub = lane & 7;
    int w0 = (n0 + 7) >> 3, w1 = (n1 + 7) >> 3, w2 = (n2 + 7) >> 3;
    if (wid >= w0 + w1 + w2) return;
    int rg, n, rbase, nA, thr, aoff, boff;
    long long offA, offB;
    if (wid < w0) {
        rg = wid << 3; n = n0; rbase = 0; nA = U;
        thr = 0x7fffffff; aoff = 0; boff = 0;
        offA = 0; offB = 2LL * U + 2LL * NB;
    } else if (wid < w0 + w1) {
        rg = (wid - w0) << 3; n = n1; rbase = n0; nA = NB;
        thr = thr1; aoff = ao1; boff = bo1;
        offA = 2LL * U; offB = 2LL * U + 2LL * NB + NI;
    } else {
        rg = (wid - w0 - w1) << 3; n = n2; rbase = n0 + n1; nA = U;
        thr = thr2; aoff = ao2; boff = bo2;
        offA = (long long)U; offB = 2LL * U + NB;
    }
    int r = rg + oct;
    bool rowok = r < n;
    int beg = 0, end = 0;
    if (rowok) { int2 be = row_be[rbase + r]; beg = be.x; end = be.y; }
    const __half* f1g = f1 + (size_t)rbase * D;
    int sb3 = sub << 3;
    // hoist own-row f1 + x0 (fp16 concat table) loads above the gather loop
    int4 hx = rowok ? *(const int4*)(f1g + (size_t)r * D + sb3)
                    : make_int4(0, 0, 0, 0);
    int x0idx = r + ((r < thr) ? aoff : boff);
    int4 hx0 = rowok ? *(const int4*)(feat + ((size_t)x0idx << 6) + sb3)
                     : make_int4(0, 0, 0, 0);
    float a0 = 0.f, a1 = 0.f, a2 = 0.f, a3 = 0.f,
          a4 = 0.f, a5 = 0.f, a6 = 0.f, a7 = 0.f;
    for (int j = beg; __any(j < end); j += UNR) {
        float v[UNR];
        unsigned o[UNR];
        int4 h[UNR];
        #pragma unroll
        for (int k = 0; k < UNR; ++k) {
            int2 ek = ev[j + k];
            bool c = (j + k) < end;
            v[k] = c ? __int_as_float(ek.y) : 0.0f;
            o[k] = c ? (((unsigned)ek.x << 6) + sb3) : 0u;
        }
        #pragma unroll
        for (int k = 0; k < UNR; ++k) GLOAD(h[k], (const void*)(f1g + o[k]));
        asm volatile("s_waitcnt vmcnt(0)" ::: "memory");
        __builtin_amdgcn_sched_barrier(0);
        #pragma unroll
        for (int k = 0; k < UNR; ++k) { EDGE_FMIX(v[k], h[k]); }
    }
    // own-row f1 (scaled) -> floats; norms reduced across the octet (lane bits 0..2)
    float2 x01 = __half22float2(*(const __half2*)&hx.x);
    float2 x23 = __half22float2(*(const __half2*)&hx.y);
    float2 x45 = __half22float2(*(const __half2*)&hx.z);
    float2 x67 = __half22float2(*(const __half2*)&hx.w);
    float s1 = x01.x * x01.x + x01.y * x01.y + x23.x * x23.x + x23.y * x23.y
             + x45.x * x45.x + x45.y * x45.y + x67.x * x67.x + x67.y * x67.y;
    float s2 = a0 * a0 + a1 * a1 + a2 * a2 + a3 * a3
             + a4 * a4 + a5 * a5 + a6 * a6 + a7 * a7;
    #pragma unroll
    for (int m = 1; m <= 4; m <<= 1) {
        s1 += __shfl_xor(s1, m, 64);
        s2 += __shfl_xor(s2, m, 64);
    }
    float inv1 = 1.0f / fmaxf(sqrtf(s1), 1e-12f);
    float inv2 = 1.0f / fmaxf(sqrtf(s2), 1e-12f);
    // x0 (fp16) -> floats
    float2 q01 = __half22float2(*(const __half2*)&hx0.x);
    float2 q23 = __half22float2(*(const __half2*)&hx0.y);
    float2 q45 = __half22float2(*(const __half2*)&hx0.z);
    float2 q67 = __half22float2(*(const __half2*)&hx0.w);
    long long orow = (r < nA) ? (offA + r) : (offB + (r - nA));
    if (rowok) {
        float4 ya, yb;
        ya.x = (q01.x + x01.x * inv1 + a0 * inv2) * (1.0f / 3.0f);
        ya.y = (q01.y + x01.y * inv1 + a1 * inv2) * (1.0f / 3.0f);
        ya.z = (q23.x + x23.x * inv1 + a2 * inv2) * (1.0f / 3.0f);
        ya.w = (q23.y + x23.y * inv1 + a3 * inv2) * (1.0f / 3.0f);
        yb.x = (q45.x + x45.x * inv1 + a4 * inv2) * (1.0f / 3.0f);
        yb.y = (q45.y + x45.y * inv1 + a5 * inv2) * (1.0f / 3.0f);
        yb.z = (q67.x + x67.x * inv1 + a6 * inv2) * (1.0f / 3.0f);
        yb.w = (q67.y + x67.y * inv1 + a7 * inv2) * (1.0f / 3.0f);
        float* op = out + orow * D + sb3;
        *(float4*)op = ya;
        *(float4*)(op + 4) = yb;
    }
}

extern "C" void kernel_launch(void* const* d_in, const int* in_sizes, int n_in,
                              void* d_out, int out_size, void* d_ws, size_t ws_size,
                              hipStream_t stream) {
    const float* users   = (const float*)d_in[0];
    const float* items   = (const float*)d_in[1];
    const float* bundles = (const float*)d_in[2];
    const float* ui_vals = (const float*)d_in[3];
    const float* bi_vals = (const float*)d_in[4];
    const float* ub_vals = (const float*)d_in[5];
    const int* ui_rows = (const int*)d_in[6];
    const int* ui_cols = (const int*)d_in[7];
    const int* bi_rows = (const int*)d_in[8];
    const int* bi_cols = (const int*)d_in[9];
    const int* ub_rows = (const int*)d_in[10];
    const int* ub_cols = (const int*)d_in[11];

    const int U  = in_sizes[0] / D;
    const int NI = in_sizes[1] / D;
    const int NB = in_sizes[2] / D;
    const int E_ui = in_sizes[3];
    const int E_bi = in_sizes[4];
    const int E_ub = in_sizes[5];

    float* out = (float*)d_out;

    const int n0 = U + NI, n1 = NB + NI, n2 = U + NB;      // per-graph row counts
    const int ntot = n0 + n1 + n2;                          // 340000
    const int nb0 = (n0 + SB_ROWS - 1) >> SB_SHIFT;         // 147
    const int nb1 = (n1 + SB_ROWS - 1) >> SB_SHIFT;         // 69
    const int nb2 = (n2 + SB_ROWS - 1) >> SB_SHIFT;         // 147
    const int nbt = nb0 + nb1 + nb2;                        // 363

    char* ws = (char*)d_ws;
    __half* feat16 = (__half*)ws; ws += (size_t)(U + NI + NB) * D * sizeof(__half); // 21.8 MB
    __half* f1     = (__half*)ws; ws += (size_t)ntot * D * sizeof(__half);          // 43.5 MB
    int2*  ev      = (int2*)ws;   ws += (size_t)nbt * CAPB * sizeof(int2);          // 47.6 MB
    int2*  row_be  = (int2*)ws;   ws += (size_t)ntot * sizeof(int2);                // 2.7 MB
    int*   gcnt    = (int*)ws;    ws += (size_t)nbt * sizeof(int);                  // 1.5 KB
    (void)ws_size;

    hipMemsetAsync(gcnt, 0, (size_t)nbt * sizeof(int), stream);

    // fp32 -> fp16 concat feature table
    cvt_feat<<<2048, 256, 0, stream>>>(users, items, bundles, (__half2*)feat16,
                                       (long long)U * (D / 2), (long long)NI * (D / 2),
                                       (long long)NB * (D / 2));

    // fused hist + reserve + scatter into per-bucket arena
    part_scatter4<<<3 * NPB, PART_T, 0, stream>>>(ui_rows, ui_cols, ui_vals,
                                                  bi_rows, bi_cols, bi_vals,
                                                  ub_rows, ub_cols, ub_vals,
                                                  E_ui, E_bi, E_ub, nb0, nb1, nb2,
                                                  gcnt, ev);
    csr_finalize4<<<nbt, FIN_T, 0, stream>>>(ev, gcnt, nb0, nb1, nb2,
                                             n0, n1, n2, row_be);

    // feature-space remap constants (col -> concat [u|i|b] index):
    // UI: identity. BI: bundles +U+NI (col<NB), items +U-NB. UB: users +0 (col<U), bundles +NI.
    const int w0 = (n0 + 7) >> 3, w1c = (n1 + 7) >> 3, w2c = (n2 + 7) >> 3;
    const int wtot = w0 + w1c + w2c;                  // 46250 waves
    const int rblocks = (wtot + 3) / 4;               // 4 waves per 256-block
    spmm_l1_all<<<rblocks, 256, 0, stream>>>(row_be, ev, feat16, n0, n1, n2,
                                             NB, U + NI, U - NB,
                                             U, 0, NI, f1);
    spmm_l2_all<<<rblocks, 256, 0, stream>>>(row_be, ev, f1, feat16,
                                             n0, n1, n2, U, NI, NB,
                                             NB, U + NI, U - NB,
                                             U, 0, NI, out);
}